// Round 7
// baseline (96.574 us; speedup 1.0000x reference)
//
#include <hip/hip_runtime.h>

#define N_ROWS 131072
#define D_COLS 256
#define B_SEG  16
#define ROWS_PER_WAVE 16
#define NWAVE (N_ROWS / ROWS_PER_WAVE)   // 8192

// Workspace layout (no zero-init needed -- every slot written every call):
//   part[NWAVE][2]    : fast-path waves write (rp, rn); straddlers write (0,0)
//   ovfl[NWAVE? no -- NWAVE][32] would be huge; straddlers are <=15 but at
//   unknown indices, so give every wave a flag + the reducer sums ovfl only
//   when flagged. Instead: ovfl[NWAVE][2] is still 64KB... Simplest: every
//   wave owns ovfl line ONLY if straddler; we allocate ovfl[128][33]:
//   straddler k (atomic ticket, <=15 of them) writes {32 sums + count} there.
// Final layout chosen:
//   part  : float[NWAVE*2]            (64 KB)
//   ovcnt : int[1]                    (#straddlers, written by kernel via atomic)
//   ovfl  : float[128][32]            (straddler partial lines, 16 KB)
// ovcnt is reset by wave 0 writing... cannot (race). Use ticket scheme:
// straddlers atomicAdd a ticket that the REDUCER resets after use; first
// timed call needs ticket==0 -> one 4-byte memset remains, but it's 4 bytes
// and could also be folded... keep memset of 4 B (cheap, <1us).

__global__ __launch_bounds__(256) void umse_main(
    const float* __restrict__ input,
    const float* __restrict__ target,
    const int*   __restrict__ batch,
    float*       __restrict__ part /* [NWAVE][2] */,
    int*         __restrict__ ovtk /* ticket */,
    float*       __restrict__ ovfl /* [128][33]: 32 sums + segbase tag */) {

    const int wave = (blockIdx.x * blockDim.x + threadIdx.x) >> 6;
    const int lane = threadIdx.x & 63;
    const int row0 = wave * ROWS_PER_WAVE;

    const float4* __restrict__ in4 = (const float4*)input;
    const float4* __restrict__ tg4 = (const float4*)target;

    const int b0 = batch[row0];
    const int b1 = batch[row0 + ROWS_PER_WAVE - 1];

    if (b0 == b1) {
        // ---- fast path: whole chunk in one segment (8177+ of 8192 waves) ----
        float rp0 = 0.f, rn0 = 0.f, rp1 = 0.f, rn1 = 0.f;
        float rp2 = 0.f, rn2 = 0.f, rp3 = 0.f, rn3 = 0.f;
        #pragma unroll
        for (int half = 0; half < 2; ++half) {
            const int base = (row0 + half * 8) * (D_COLS / 4) + lane;
            float4 xa[8], ta[8];
            #pragma unroll
            for (int i = 0; i < 8; ++i) xa[i] = in4[base + i * (D_COLS / 4)];
            #pragma unroll
            for (int i = 0; i < 8; ++i) ta[i] = tg4[base + i * (D_COLS / 4)];
            #pragma unroll
            for (int i = 0; i < 8; ++i) {
                float d;
                d = xa[i].x - ta[i].x; rp0 += d * d;  d = xa[i].x + ta[i].x; rn0 += d * d;
                d = xa[i].y - ta[i].y; rp1 += d * d;  d = xa[i].y + ta[i].y; rn1 += d * d;
                d = xa[i].z - ta[i].z; rp2 += d * d;  d = xa[i].z + ta[i].z; rn2 += d * d;
                d = xa[i].w - ta[i].w; rp3 += d * d;  d = xa[i].w + ta[i].w; rn3 += d * d;
            }
        }
        float rp = (rp0 + rp1) + (rp2 + rp3);
        float rn = (rn0 + rn1) + (rn2 + rn3);
        #pragma unroll
        for (int off = 32; off; off >>= 1) {
            rp += __shfl_down(rp, off);
            rn += __shfl_down(rn, off);
        }
        if (lane == 0) {
            float2* p = (float2*)&part[wave * 2];
            *p = make_float2(rp, rn);
        }
    } else {
        // ---- slow path: chunk straddles segment boundaries (<=15 waves) ----
        // Accumulate per-segment (relative to b0: segments b0..b0+? ; a 16-row
        // chunk can span at most 16 distinct segments; b in [b0, b0+15]).
        float lp[B_SEG], ln[B_SEG];   // indexed by (b - b0), b-b0 in [0,15]
        #pragma unroll
        for (int k = 0; k < B_SEG; ++k) { lp[k] = 0.f; ln[k] = 0.f; }
        for (int i = 0; i < ROWS_PER_WAVE; ++i) {
            const int r = row0 + i;
            const int b = batch[r];
            const float4 x = in4[r * (D_COLS / 4) + lane];
            const float4 t = tg4[r * (D_COLS / 4) + lane];
            float d;
            float p = 0.f, n = 0.f;
            d = x.x - t.x; p += d * d;  d = x.x + t.x; n += d * d;
            d = x.y - t.y; p += d * d;  d = x.y + t.y; n += d * d;
            d = x.z - t.z; p += d * d;  d = x.z + t.z; n += d * d;
            d = x.w - t.w; p += d * d;  d = x.w + t.w; n += d * d;
            #pragma unroll
            for (int off = 32; off; off >>= 1) {
                p += __shfl_down(p, off);
                n += __shfl_down(n, off);
            }
            // lane 0 holds the row totals; broadcast index, accumulate on lane 0
            if (lane == 0) {
                const int k = b - b0;   // 0..15
                #pragma unroll
                for (int kk = 0; kk < B_SEG; ++kk) {  // static indexing
                    if (kk == k) { lp[kk] += p; ln[kk] += n; }
                }
            }
        }
        if (lane == 0) {
            part[wave * 2 + 0] = 0.f;
            part[wave * 2 + 1] = 0.f;
            const int slot = atomicAdd(ovtk, 1);       // <=15 total, no contention
            float* line = &ovfl[slot * 33];
            #pragma unroll
            for (int k = 0; k < B_SEG; ++k) {
                line[2 * k + 0] = lp[k];
                line[2 * k + 1] = ln[k];
            }
            line[32] = (float)b0;                      // tag
        }
    }
}

// Reduce: 1024 threads. part[NWAVE][2] gathered by segment via batch[], plus
// overflow lines. Then min-pair sum -> out[0]; reset ticket for next replay.
__global__ __launch_bounds__(1024) void umse_final(
    const float* __restrict__ part,
    const int*   __restrict__ batch,
    int*         __restrict__ ovtk,
    const float* __restrict__ ovfl,
    float*       __restrict__ out) {

    __shared__ float gacc[B_SEG * 2];          // global per-segment sums
    const int tid = threadIdx.x;
    if (tid < B_SEG * 2) gacc[tid] = 0.f;
    __syncthreads();

    // each thread sums waves tid, tid+1024, ... into per-thread locals keyed
    // by segment; waves are sorted by segment, so a thread touches few segs.
    float lp = 0.f, ln = 0.f;
    int cur = -1;
    for (int w = tid; w < NWAVE; w += 1024) {
        const int b = batch[w * ROWS_PER_WAVE];   // segment of fast-path wave
        if (b != cur) {
            if (cur >= 0) {
                atomicAdd(&gacc[cur * 2 + 0], lp);
                atomicAdd(&gacc[cur * 2 + 1], ln);
            }
            cur = b; lp = 0.f; ln = 0.f;
        }
        lp += part[w * 2 + 0];
        ln += part[w * 2 + 1];
    }
    if (cur >= 0) {
        atomicAdd(&gacc[cur * 2 + 0], lp);
        atomicAdd(&gacc[cur * 2 + 1], ln);
    }
    __syncthreads();

    if (tid == 0) {
        // fold in overflow lines (<=15), then min-pair sum
        const int nov = *ovtk;
        float acc2[B_SEG * 2];
        #pragma unroll
        for (int k = 0; k < B_SEG * 2; ++k) acc2[k] = gacc[k];
        for (int s = 0; s < nov; ++s) {
            const float* line = &ovfl[s * 33];
            const int base = (int)line[32];
            for (int k = 0; k < B_SEG; ++k) {
                const int b = base + k;
                if (b < B_SEG) {
                    acc2[b * 2 + 0] += line[2 * k + 0];
                    acc2[b * 2 + 1] += line[2 * k + 1];
                }
            }
        }
        float s = 0.f;
        #pragma unroll
        for (int b = 0; b < B_SEG; ++b)
            s += fminf(acc2[2 * b + 0], acc2[2 * b + 1]);
        out[0] = s;
        *ovtk = 0;   // reset ticket for the next graph replay
    }
}

extern "C" void kernel_launch(void* const* d_in, const int* in_sizes, int n_in,
                              void* d_out, int out_size, void* d_ws, size_t ws_size,
                              hipStream_t stream) {
    const float* input  = (const float*)d_in[0];
    const float* target = (const float*)d_in[1];
    const int*   batch  = (const int*)d_in[2];

    float* part = (float*)d_ws;                                  // 64 KB
    int*   ovtk = (int*)((char*)d_ws + NWAVE * 2 * sizeof(float));
    float* ovfl = (float*)((char*)ovtk + 256);                   // 128*33*4 B

    // 4-byte ticket reset for the very first timed call (d_ws poisoned 0xAA);
    // umse_final resets it thereafter. Tiny node, no dependency cost vs 8KB.
    hipMemsetAsync(ovtk, 0, sizeof(int), stream);

    const int blocks = NWAVE * 64 / 256;    // 2048 blocks, 256 thr
    umse_main<<<blocks, 256, 0, stream>>>(input, target, batch, part, ovtk, ovfl);
    umse_final<<<1, 1024, 0, stream>>>(part, batch, ovtk, ovfl, (float*)d_out);
}

// Round 8
// 59.476 us; speedup vs baseline: 1.6237x; 1.6237x over previous
//
#include <hip/hip_runtime.h>

#define N_ROWS 131072
#define D_COLS 256
#define B_SEG  16
#define ROWS_PER_WAVE 16
#define NSLOT 64   // accumulator slots, each 32 floats = 128 B (own cache line)

typedef float f32x4 __attribute__((ext_vector_type(4)));

// One wave (64 lanes) handles ROWS_PER_WAVE contiguous rows.
// Lane l loads float4 at column 4*l: 64 lanes * 16B = 256 floats = one row.
// input is loaded normally (stays L3-resident: 128 MB < 256 MB L3);
// target is loaded non-temporally (streams from HBM, doesn't thrash L3).
__global__ __launch_bounds__(256) void umse_main(
    const float* __restrict__ input,
    const float* __restrict__ target,
    const int*   __restrict__ batch,
    float*       __restrict__ acc /* [NSLOT][B_SEG*2] */) {

    const int wave = (blockIdx.x * blockDim.x + threadIdx.x) >> 6;
    const int lane = threadIdx.x & 63;
    const int row0 = wave * ROWS_PER_WAVE;
    float* __restrict__ slot = acc + (blockIdx.x & (NSLOT - 1)) * (B_SEG * 2);

    const f32x4* __restrict__ in4 = (const f32x4*)input;
    const f32x4* __restrict__ tg4 = (const f32x4*)target;

    const int b0 = batch[row0];
    const int b1 = batch[row0 + ROWS_PER_WAVE - 1];

    if (b0 == b1) {
        // ---- fast path: whole chunk in one segment (8177+ of 8192 waves) ----
        float rp0 = 0.f, rn0 = 0.f, rp1 = 0.f, rn1 = 0.f;
        float rp2 = 0.f, rn2 = 0.f, rp3 = 0.f, rn3 = 0.f;
        #pragma unroll
        for (int half = 0; half < 2; ++half) {
            const int base = (row0 + half * 8) * (D_COLS / 4) + lane;
            f32x4 xa[8], ta[8];
            #pragma unroll
            for (int i = 0; i < 8; ++i) xa[i] = in4[base + i * (D_COLS / 4)];
            #pragma unroll
            for (int i = 0; i < 8; ++i)
                ta[i] = __builtin_nontemporal_load(&tg4[base + i * (D_COLS / 4)]);
            #pragma unroll
            for (int i = 0; i < 8; ++i) {
                float d;
                d = xa[i].x - ta[i].x; rp0 += d * d;  d = xa[i].x + ta[i].x; rn0 += d * d;
                d = xa[i].y - ta[i].y; rp1 += d * d;  d = xa[i].y + ta[i].y; rn1 += d * d;
                d = xa[i].z - ta[i].z; rp2 += d * d;  d = xa[i].z + ta[i].z; rn2 += d * d;
                d = xa[i].w - ta[i].w; rp3 += d * d;  d = xa[i].w + ta[i].w; rn3 += d * d;
            }
        }
        float rp = (rp0 + rp1) + (rp2 + rp3);
        float rn = (rn0 + rn1) + (rn2 + rn3);
        #pragma unroll
        for (int off = 32; off; off >>= 1) {
            rp += __shfl_down(rp, off);
            rn += __shfl_down(rn, off);
        }
        if (lane == 0) {
            atomicAdd(&slot[b0 * 2 + 0], rp);
            atomicAdd(&slot[b0 * 2 + 1], rn);
        }
    } else {
        // ---- slow path: chunk straddles a segment boundary (<=15 waves) ----
        for (int i = 0; i < ROWS_PER_WAVE; ++i) {
            const int r = row0 + i;
            const int b = batch[r];
            const f32x4 x = in4[r * (D_COLS / 4) + lane];
            const f32x4 t = __builtin_nontemporal_load(&tg4[r * (D_COLS / 4) + lane]);
            float d;
            float p = 0.f, n = 0.f;
            d = x.x - t.x; p += d * d;  d = x.x + t.x; n += d * d;
            d = x.y - t.y; p += d * d;  d = x.y + t.y; n += d * d;
            d = x.z - t.z; p += d * d;  d = x.z + t.z; n += d * d;
            d = x.w - t.w; p += d * d;  d = x.w + t.w; n += d * d;
            #pragma unroll
            for (int off = 32; off; off >>= 1) {
                p += __shfl_down(p, off);
                n += __shfl_down(n, off);
            }
            if (lane == 0) {
                atomicAdd(&slot[b * 2 + 0], p);
                atomicAdd(&slot[b * 2 + 1], n);
            }
        }
    }
}

// Reduce [NSLOT][32] -> out = sum_b min(lp[b], ln[b]). One wave.
__global__ void umse_final(const float* __restrict__ acc, float* __restrict__ out) {
    const int lane = threadIdx.x;  // 0..63
    float s = 0.f;
    if (lane < B_SEG * 2) {
        #pragma unroll
        for (int sl = 0; sl < NSLOT; ++sl)
            s += acc[sl * (B_SEG * 2) + lane];
    }
    const float partner = __shfl_xor(s, 1);
    const float m = fminf(s, partner);              // both lanes of a pair hold the min
    float contrib = ((lane < B_SEG * 2) && ((lane & 1) == 0)) ? m : 0.f;
    #pragma unroll
    for (int off = 32; off; off >>= 1)
        contrib += __shfl_down(contrib, off);
    if (lane == 0) out[0] = contrib;
}

extern "C" void kernel_launch(void* const* d_in, const int* in_sizes, int n_in,
                              void* d_out, int out_size, void* d_ws, size_t ws_size,
                              hipStream_t stream) {
    const float* input  = (const float*)d_in[0];
    const float* target = (const float*)d_in[1];
    const int*   batch  = (const int*)d_in[2];
    float* acc = (float*)d_ws;   // NSLOT*32*4 = 8 KB of scratch

    // zero the slotted accumulators every call (d_ws is not re-poisoned between replays)
    hipMemsetAsync(acc, 0, NSLOT * B_SEG * 2 * sizeof(float), stream);

    const int waves  = N_ROWS / ROWS_PER_WAVE;      // 8192
    const int blocks = waves * 64 / 256;            // 2048 blocks, 256 thr
    umse_main<<<blocks, 256, 0, stream>>>(input, target, batch, acc);
    umse_final<<<1, 64, 0, stream>>>(acc, (float*)d_out);
}

// Round 9
// 54.733 us; speedup vs baseline: 1.7645x; 1.0867x over previous
//
#include <hip/hip_runtime.h>

#define N_ROWS 131072
#define D_COLS 256
#define B_SEG  16
#define ROWS_PER_WAVE 16
#define NSLOT 64   // accumulator slots, each 32 floats = 128 B (own cache line)

// One wave (64 lanes) handles ROWS_PER_WAVE contiguous rows.
// Lane l loads float4 at column 4*l: 64 lanes * 16B = 256 floats = one row.
// Fast path stages 8 rows of input+target into registers (16 independent
// dwordx4 loads in flight) before consuming.
__global__ __launch_bounds__(256) void umse_main(
    const float* __restrict__ input,
    const float* __restrict__ target,
    const int*   __restrict__ batch,
    float*       __restrict__ acc /* [NSLOT][B_SEG*2] */) {

    const int wave = (blockIdx.x * blockDim.x + threadIdx.x) >> 6;
    const int lane = threadIdx.x & 63;
    const int row0 = wave * ROWS_PER_WAVE;
    float* __restrict__ slot = acc + (blockIdx.x & (NSLOT - 1)) * (B_SEG * 2);

    const float4* __restrict__ in4 = (const float4*)input;
    const float4* __restrict__ tg4 = (const float4*)target;

    const int b0 = batch[row0];
    const int b1 = batch[row0 + ROWS_PER_WAVE - 1];

    if (b0 == b1) {
        // ---- fast path: whole chunk in one segment (8177+ of 8192 waves) ----
        float rp0 = 0.f, rn0 = 0.f, rp1 = 0.f, rn1 = 0.f;
        float rp2 = 0.f, rn2 = 0.f, rp3 = 0.f, rn3 = 0.f;
        #pragma unroll
        for (int half = 0; half < 2; ++half) {
            const int base = (row0 + half * 8) * (D_COLS / 4) + lane;
            float4 xa[8], ta[8];
            #pragma unroll
            for (int i = 0; i < 8; ++i) xa[i] = in4[base + i * (D_COLS / 4)];
            #pragma unroll
            for (int i = 0; i < 8; ++i) ta[i] = tg4[base + i * (D_COLS / 4)];
            #pragma unroll
            for (int i = 0; i < 8; ++i) {
                float d;
                d = xa[i].x - ta[i].x; rp0 += d * d;  d = xa[i].x + ta[i].x; rn0 += d * d;
                d = xa[i].y - ta[i].y; rp1 += d * d;  d = xa[i].y + ta[i].y; rn1 += d * d;
                d = xa[i].z - ta[i].z; rp2 += d * d;  d = xa[i].z + ta[i].z; rn2 += d * d;
                d = xa[i].w - ta[i].w; rp3 += d * d;  d = xa[i].w + ta[i].w; rn3 += d * d;
            }
        }
        float rp = (rp0 + rp1) + (rp2 + rp3);
        float rn = (rn0 + rn1) + (rn2 + rn3);
        #pragma unroll
        for (int off = 32; off; off >>= 1) {
            rp += __shfl_down(rp, off);
            rn += __shfl_down(rn, off);
        }
        if (lane == 0) {
            atomicAdd(&slot[b0 * 2 + 0], rp);
            atomicAdd(&slot[b0 * 2 + 1], rn);
        }
    } else {
        // ---- slow path: chunk straddles a segment boundary (<=15 waves) ----
        for (int i = 0; i < ROWS_PER_WAVE; ++i) {
            const int r = row0 + i;
            const int b = batch[r];
            const float4 x = in4[r * (D_COLS / 4) + lane];
            const float4 t = tg4[r * (D_COLS / 4) + lane];
            float d;
            float p = 0.f, n = 0.f;
            d = x.x - t.x; p += d * d;  d = x.x + t.x; n += d * d;
            d = x.y - t.y; p += d * d;  d = x.y + t.y; n += d * d;
            d = x.z - t.z; p += d * d;  d = x.z + t.z; n += d * d;
            d = x.w - t.w; p += d * d;  d = x.w + t.w; n += d * d;
            #pragma unroll
            for (int off = 32; off; off >>= 1) {
                p += __shfl_down(p, off);
                n += __shfl_down(n, off);
            }
            if (lane == 0) {
                atomicAdd(&slot[b * 2 + 0], p);
                atomicAdd(&slot[b * 2 + 1], n);
            }
        }
    }
}

// Reduce [NSLOT][32] -> out = sum_b min(lp[b], ln[b]). One wave.
__global__ void umse_final(const float* __restrict__ acc, float* __restrict__ out) {
    const int lane = threadIdx.x;  // 0..63
    float s = 0.f;
    if (lane < B_SEG * 2) {
        #pragma unroll
        for (int sl = 0; sl < NSLOT; ++sl)
            s += acc[sl * (B_SEG * 2) + lane];
    }
    const float partner = __shfl_xor(s, 1);
    const float m = fminf(s, partner);              // both lanes of a pair hold the min
    float contrib = ((lane < B_SEG * 2) && ((lane & 1) == 0)) ? m : 0.f;
    #pragma unroll
    for (int off = 32; off; off >>= 1)
        contrib += __shfl_down(contrib, off);
    if (lane == 0) out[0] = contrib;
}

extern "C" void kernel_launch(void* const* d_in, const int* in_sizes, int n_in,
                              void* d_out, int out_size, void* d_ws, size_t ws_size,
                              hipStream_t stream) {
    const float* input  = (const float*)d_in[0];
    const float* target = (const float*)d_in[1];
    const int*   batch  = (const int*)d_in[2];
    float* acc = (float*)d_ws;   // NSLOT*32*4 = 8 KB of scratch

    // zero the slotted accumulators every call (d_ws is not re-poisoned between replays)
    hipMemsetAsync(acc, 0, NSLOT * B_SEG * 2 * sizeof(float), stream);

    const int waves  = N_ROWS / ROWS_PER_WAVE;      // 8192
    const int blocks = waves * 64 / 256;            // 2048 blocks, 256 thr
    umse_main<<<blocks, 256, 0, stream>>>(input, target, batch, acc);
    umse_final<<<1, 64, 0, stream>>>(acc, (float*)d_out);
}